// Round 11
// baseline (1256.965 us; speedup 1.0000x reference)
//
#include <hip/hip_runtime.h>

#define Bq   16
#define Sq   512
#define Vq   128
#define NCq  10000

typedef __attribute__((ext_vector_type(8))) short short8v;
typedef __attribute__((ext_vector_type(4))) float f32x4;

// ---- workspace layout (float offsets) ----
#define OFF_XPF    0u          // [4 bg][512 t][96 r4][4 b][4 e] f32 (biases + r*wvr folded)
#define OFF_P1F    3145728u    // [512 t][16 b][128 j] f32 (b1 + r*wvr1 folded)
#define OFF_WTIH   4194304u    // [128 k][384 g] W_ih[:, :V]^T
#define OFF_WVRIH  4243456u    // [384]
#define OFF_WVR1   4243840u    // [128]
#define OFF_WVB    4243968u    // [128]
#define OFF_PO     4244096u    // int [512 t][16 b]

#define PLN 136
#define PLSZ (16*PLN+8)

__device__ __forceinline__ unsigned cvt_pk_bf16(float a, float b) {
    unsigned r;
    asm("v_cvt_pk_bf16_f32 %0, %1, %2" : "=v"(r) : "v"(a), "v"(b));
    return r;
}
__device__ __forceinline__ void barrier_lgkm() {
    asm volatile("s_waitcnt lgkmcnt(0)" ::: "memory");
    __builtin_amdgcn_sched_barrier(0);
    __builtin_amdgcn_s_barrier();
    __builtin_amdgcn_sched_barrier(0);
}
__device__ __forceinline__ void wait_vm4() {
    asm volatile("s_waitcnt vmcnt(4)" ::: "memory");
    __builtin_amdgcn_sched_barrier(0);
}
__device__ __forceinline__ void gload_lds16(const void* g, void* l) {
    __builtin_amdgcn_global_load_lds(
        (const __attribute__((address_space(1))) unsigned int*)g,
        (__attribute__((address_space(3))) unsigned int*)l, 16, 0, 0);
}

// ============ K0: transpose, small vectors, prev-occurrence, gamma ============
__global__ __launch_bounds__(256) void k0_prep(
    const int* __restrict__ c_seq, const int* __restrict__ d_seq,
    const float* __restrict__ D1_w,
    const float* __restrict__ W_ih,
    const float* __restrict__ v_r, const float* __restrict__ v_beta,
    const float* __restrict__ m2W1,
    float* __restrict__ ws, float* __restrict__ gamma_out)
{
    const int blk = blockIdx.x, tid = threadIdx.x;

    if (blk < 128) {
        float* WTIH = ws + OFF_WTIH;
        int base = blk * 384;
        for (int i = tid; i < 384; i += 256) {
            int e = base + i;
            int k = e / 384, g = e % 384;
            WTIH[e] = W_ih[g * 256 + k];
        }
    } else if (blk == 128) {
        float* WVRIH = ws + OFF_WVRIH;
        float* WVR1  = ws + OFF_WVR1;
        float* WVB   = ws + OFF_WVB;
        for (int g = tid; g < 384; g += 256) {
            float a = 0.f;
            for (int k = 0; k < 128; ++k) a = fmaf(v_r[k], W_ih[g * 256 + 128 + k], a);
            WVRIH[g] = a;
        }
        if (tid < 128) {
            float a = 0.f, b = 0.f;
            for (int k = 0; k < 128; ++k) {
                a = fmaf(v_r[k],    m2W1[(256 + k) * 128 + tid], a);
                b = fmaf(v_beta[k], m2W1[k * 128 + tid],         b);
            }
            WVR1[tid] = a; WVB[tid] = b;
        }
    } else if (blk < 145) {
        const int b = blk - 129;
        __shared__ int cs[Sq];
        for (int i = tid; i < Sq; i += 256) cs[i] = c_seq[b * Sq + i];
        __syncthreads();
        int* PO = (int*)(ws + OFF_PO);
        for (int t = tid; t < Sq; t += 256) {
            int c = cs[t];
            int po = -1;
            for (int u = t - 1; u >= 0; --u) if (cs[u] == c) { po = u; break; }
            PO[t * 16 + b] = po;
        }
    } else {
        const int b = blk - 145;
        for (int s = tid; s < Sq; s += 256)
            gamma_out[b * Sq + s] = D1_w[d_seq[b * Sq + s]];
    }
}

// ============ K1: batched GEMM -> XPF (f32) | P1F (f32), biases folded ============
__global__ __launch_bounds__(256) void k1_gemm(
    const int* __restrict__ d_seq, const float* __restrict__ D2_w,
    const float* __restrict__ m2W1,
    const float* __restrict__ b_ih, const float* __restrict__ b_hh,
    const float* __restrict__ r_seq, const float* __restrict__ m2b1,
    float* __restrict__ ws)
{
    __shared__ float As[64 * 128];
    __shared__ float Bs[128 * 64];
    const int blk = blockIdx.x, tid = threadIdx.x;
    const int nc = blk & 7;
    const int m0 = (blk >> 3) * 64;
    const float* WTIH = ws + OFF_WTIH;

    const float4* D2v = (const float4*)D2_w;
    for (int e = tid; e < 2048; e += 256) {
        int r = e >> 5, q = e & 31;
        int d = d_seq[m0 + r];
        *(float4*)&As[r * 128 + 4 * q] = D2v[d * 32 + q];
    }
    for (int e = tid; e < 2048; e += 256) {
        int k = e >> 4, q = e & 15;
        float4 v;
        if (nc < 6) v = *(const float4*)&WTIH[k * 384 + nc * 64 + 4 * q];
        else        v = *(const float4*)&m2W1[(128 + k) * 128 + (nc - 6) * 64 + 4 * q];
        *(float4*)&Bs[k * 64 + 4 * q] = v;
    }
    __syncthreads();

    const int tx = tid & 15, ty = tid >> 4;
    const int c0 = 4 * tx, r0 = 4 * ty;
    float acc[4][4];
#pragma unroll
    for (int i = 0; i < 4; ++i)
#pragma unroll
        for (int j = 0; j < 4; ++j) acc[i][j] = 0.f;

    for (int k = 0; k < 128; ++k) {
        float4 bv = *(const float4*)&Bs[k * 64 + c0];
#pragma unroll
        for (int i = 0; i < 4; ++i) {
            float a = As[(r0 + i) * 128 + k];
            acc[i][0] = fmaf(a, bv.x, acc[i][0]);
            acc[i][1] = fmaf(a, bv.y, acc[i][1]);
            acc[i][2] = fmaf(a, bv.z, acc[i][2]);
            acc[i][3] = fmaf(a, bv.w, acc[i][3]);
        }
    }

    float rsv[4];
#pragma unroll
    for (int i = 0; i < 4; ++i) rsv[i] = r_seq[m0 + r0 + i];

    if (nc < 6) {
        const int grow0 = nc * 64 + c0;
        float4 bi  = *(const float4*)&b_ih[grow0];
        float4 wv4 = *(const float4*)&(ws + OFF_WVRIH)[grow0];
        float4 bh4 = make_float4(0.f, 0.f, 0.f, 0.f);
        if (nc < 4) bh4 = *(const float4*)&b_hh[grow0];   // r,z gates get b_hh folded
        float* XPF = ws + OFF_XPF;
        const int r4 = grow0 >> 2;
#pragma unroll
        for (int i = 0; i < 4; ++i) {
            int row = m0 + r0 + i;
            int t = row & 511, bb = row >> 9;
            float4 v;
            v.x = acc[i][0] + bi.x + bh4.x + rsv[i] * wv4.x;
            v.y = acc[i][1] + bi.y + bh4.y + rsv[i] * wv4.y;
            v.z = acc[i][2] + bi.z + bh4.z + rsv[i] * wv4.z;
            v.w = acc[i][3] + bi.w + bh4.w + rsv[i] * wv4.w;
            *(float4*)&XPF[((size_t)((bb >> 2) * 512 + t)) * 1536 + r4 * 16 + (bb & 3) * 4] = v;
        }
    } else {
        const int j0 = (nc - 6) * 64 + c0;
        float4 b1v = *(const float4*)&m2b1[j0];
        float4 wr1 = *(const float4*)&(ws + OFF_WVR1)[j0];
        float* P1F = ws + OFF_P1F;
#pragma unroll
        for (int i = 0; i < 4; ++i) {
            int row = m0 + r0 + i;
            int t = row & 511, bb = row >> 9;
            float4 v;
            v.x = acc[i][0] + b1v.x + rsv[i] * wr1.x;
            v.y = acc[i][1] + b1v.y + rsv[i] * wr1.y;
            v.z = acc[i][2] + b1v.z + rsv[i] * wr1.z;
            v.w = acc[i][3] + b1v.w + rsv[i] * wr1.w;
            *(float4*)&P1F[((size_t)(t * 16 + bb)) * 128 + j0] = v;
        }
    }
}

// ============ K2: blk 0..3: GRU (4 batches, 8 waves). blk 4: beta, ONE wave, 16 batches, NO barriers ============
__global__ __launch_bounds__(512, 1) void k2_scan(
    const float* __restrict__ W_hh, const float* __restrict__ b_hh,
    const float* __restrict__ m2W2, const float* __restrict__ m2b2,
    const float* __restrict__ m2W3, const float* __restrict__ m2b3,
    float* __restrict__ ws,
    float* __restrict__ hseq_out, float* __restrict__ beta_out)
{
    __shared__ __align__(16) unsigned char smem[41504];
    const int tid = threadIdx.x;
    const int l = tid & 63, wv = tid >> 6;
    const int qq = l >> 4, cb = l & 15;
    const int bgid = blockIdx.x;

    if (bgid < 4) {
        // ---------------- GRU, batches 4*bgid .. 4*bgid+3 ----------------
        unsigned short* hP  = (unsigned short*)smem;                // [2][PLSZ]
        unsigned char*  xsl = smem + 8736;                          // 4 slots x 8192 B
        const float* XPF = ws + OFF_XPF;

        short8v aH0[4], aH1[4], aH2[4];
#pragma unroll
        for (int kf = 0; kf < 4; ++kf) {
            const int kb = kf * 32 + qq * 8;
            const float* w0 = W_hh + (0 * 128 + 16 * wv + cb) * 128 + kb;
            const float* w1 = W_hh + (1 * 128 + 16 * wv + cb) * 128 + kb;
            const float* w2 = W_hh + (2 * 128 + 16 * wv + cb) * 128 + kb;
            short8v h0, h1, h2;
#pragma unroll
            for (int e = 0; e < 8; ++e) {
                unsigned u0 = __builtin_bit_cast(unsigned, w0[e]);
                unsigned u1 = __builtin_bit_cast(unsigned, w1[e]);
                unsigned u2 = __builtin_bit_cast(unsigned, w2[e]);
                h0[e] = (short)((u0 + 0x7fffu + ((u0 >> 16) & 1u)) >> 16);
                h1[e] = (short)((u1 + 0x7fffu + ((u1 >> 16) & 1u)) >> 16);
                h2[e] = (short)((u2 + 0x7fffu + ((u2 >> 16) & 1u)) >> 16);
            }
            aH0[kf] = h0; aH1[kf] = h1; aH2[kf] = h2;
        }
        f32x4 bhn4;
        {
            float4 t4 = *(const float4*)&b_hh[256 + 16 * wv + 4 * qq];
            bhn4[0] = t4.x; bhn4[1] = t4.y; bhn4[2] = t4.z; bhn4[3] = t4.w;
        }

        float* hp = hseq_out + ((size_t)((bgid * 4 + (cb & 3)) * 512)) * 128 + 16 * wv + 4 * qq;
        float hold[4] = {0.f, 0.f, 0.f, 0.f};
        for (int i = tid; i < 2 * PLSZ; i += 512) hP[i] = 0;
#pragma unroll
        for (int s = 0; s < 3; ++s)
            gload_lds16(XPF + ((size_t)(bgid * 512 + s)) * 1536 + tid * 4,
                        xsl + s * 8192 + tid * 16);
        __syncthreads();   // drains prologue vmcnt + publishes plane zeros

        const float NL2E = -1.44269504f, L2E2 = 2.88539008f;
        for (int t = 0; t < 512; ++t) {
            if (t < 509)
                gload_lds16(XPF + ((size_t)(bgid * 512 + t + 3)) * 1536 + tid * 4,
                            xsl + ((t + 3) & 3) * 8192 + tid * 16);

            const float* xc = (const float*)(xsl + (t & 3) * 8192) +
                              (4 * wv + qq) * 16 + (cb & 3) * 4;
            f32x4 px0 = *(const f32x4*)(xc);
            f32x4 px1 = *(const f32x4*)(xc + 512);
            f32x4 px2 = *(const f32x4*)(xc + 1024);

            const unsigned short* HI = hP + (t & 1) * PLSZ;
            unsigned short* HIn = hP + ((t + 1) & 1) * PLSZ;

            f32x4 C0a = px0, C1a = px1, C2a = bhn4;
            f32x4 C0b = {0.f,0.f,0.f,0.f}, C1b = {0.f,0.f,0.f,0.f}, C2b = {0.f,0.f,0.f,0.f};
            {
                short8v B0 = *(const short8v*)(HI + cb * PLN + 0 * 32 + qq * 8);
                short8v B1 = *(const short8v*)(HI + cb * PLN + 1 * 32 + qq * 8);
                short8v B2 = *(const short8v*)(HI + cb * PLN + 2 * 32 + qq * 8);
                short8v B3 = *(const short8v*)(HI + cb * PLN + 3 * 32 + qq * 8);
                C0a = __builtin_amdgcn_mfma_f32_16x16x32_bf16(aH0[0], B0, C0a, 0, 0, 0);
                C1a = __builtin_amdgcn_mfma_f32_16x16x32_bf16(aH1[0], B0, C1a, 0, 0, 0);
                C2a = __builtin_amdgcn_mfma_f32_16x16x32_bf16(aH2[0], B0, C2a, 0, 0, 0);
                C0b = __builtin_amdgcn_mfma_f32_16x16x32_bf16(aH0[1], B1, C0b, 0, 0, 0);
                C1b = __builtin_amdgcn_mfma_f32_16x16x32_bf16(aH1[1], B1, C1b, 0, 0, 0);
                C2b = __builtin_amdgcn_mfma_f32_16x16x32_bf16(aH2[1], B1, C2b, 0, 0, 0);
                C0a = __builtin_amdgcn_mfma_f32_16x16x32_bf16(aH0[2], B2, C0a, 0, 0, 0);
                C1a = __builtin_amdgcn_mfma_f32_16x16x32_bf16(aH1[2], B2, C1a, 0, 0, 0);
                C2a = __builtin_amdgcn_mfma_f32_16x16x32_bf16(aH2[2], B2, C2a, 0, 0, 0);
                C0b = __builtin_amdgcn_mfma_f32_16x16x32_bf16(aH0[3], B3, C0b, 0, 0, 0);
                C1b = __builtin_amdgcn_mfma_f32_16x16x32_bf16(aH1[3], B3, C1b, 0, 0, 0);
                C2b = __builtin_amdgcn_mfma_f32_16x16x32_bf16(aH2[3], B3, C2b, 0, 0, 0);
            }
            float hnew[4];
#pragma unroll
            for (int i = 0; i < 4; ++i) {
                float pr = C0a[i] + C0b[i];
                float pz = C1a[i] + C1b[i];
                float hn = C2a[i] + C2b[i];
                float r = __builtin_amdgcn_rcpf(1.f + __builtin_amdgcn_exp2f(pr * NL2E));
                float z = __builtin_amdgcn_rcpf(1.f + __builtin_amdgcn_exp2f(pz * NL2E));
                float npre = fmaf(r, hn, px2[i]);
                float n = fmaf(-2.f, __builtin_amdgcn_rcpf(1.f + __builtin_amdgcn_exp2f(npre * L2E2)), 1.f);
                float hv = fmaf(z, hold[i] - n, n);
                hold[i] = hv;
                hnew[i] = hv;
            }
            if (cb < 4) {
                *(float4*)hp = make_float4(hnew[0], hnew[1], hnew[2], hnew[3]);
                uint2 hw;
                hw.x = cvt_pk_bf16(hnew[0], hnew[1]);
                hw.y = cvt_pk_bf16(hnew[2], hnew[3]);
                *(uint2*)(HIn + cb * PLN + 16 * wv + 4 * qq) = hw;
            }
            hp += 128;
            wait_vm4();
            barrier_lgkm();
        }
    } else {
        // ---------------- beta scan: ONE wave, all 16 batches, barrier-free ----------------
        if (tid >= 64) return;
        float* bhL = (float*)smem;                        // [16][512] f32 = 32 KB
        const float* P1F = ws + OFF_P1F;
        const int* POg = (const int*)(ws + OFF_PO);

        // A-fragments: 8 M-tiles of W2T (rows 16m+cb, k = kf*32+qq*8+e)
        short8v aH[8][4];
#pragma unroll
        for (int m = 0; m < 8; ++m)
#pragma unroll
            for (int kf = 0; kf < 4; ++kf) {
                short8v hi;
#pragma unroll
                for (int e = 0; e < 8; ++e) {
                    unsigned u = __builtin_bit_cast(unsigned,
                        m2W2[(kf * 32 + qq * 8 + e) * 128 + 16 * m + cb]);
                    hi[e] = (short)((u + 0x7fffu + ((u >> 16) & 1u)) >> 16);
                }
                aH[m][kf] = hi;
            }
        f32x4 w3C[8], b2C[8];
#pragma unroll
        for (int m = 0; m < 8; ++m) {
            w3C[m] = __builtin_bit_cast(f32x4, *(const float4*)&m2W3[16 * m + 4 * qq]);
            b2C[m] = __builtin_bit_cast(f32x4, *(const float4*)&m2b2[16 * m + 4 * qq]);
        }
        f32x4 wvb4[8];
#pragma unroll
        for (int k2i = 0; k2i < 8; ++k2i)
            wvb4[k2i] = __builtin_bit_cast(f32x4,
                *(const float4*)&(ws + OFF_WVB)[(k2i >> 1) * 32 + qq * 8 + (k2i & 1) * 4]);
        const float b3v = m2b3[0];
        const float* p1base = P1F + cb * 128 + qq * 8;

        f32x4 pA[8], pB[8];
#pragma unroll
        for (int k2i = 0; k2i < 8; ++k2i) {
            pA[k2i] = __builtin_bit_cast(f32x4,
                *(const float4*)&p1base[(k2i >> 1) * 32 + (k2i & 1) * 4]);
            pB[k2i] = __builtin_bit_cast(f32x4,
                *(const float4*)&p1base[2048 + (k2i >> 1) * 32 + (k2i & 1) * 4]);
        }
        int poCur = POg[cb];
        int poNxt = POg[16 + cb];
        float btap = 0.f, bpPre = 0.f;

        for (int t = 0; t < 512; ++t) {
            float bp = (poCur == t - 1) ? btap : bpPre;
            // h1 B-fragments in-register
            short8v Bf[4];
#pragma unroll
            for (int kf = 0; kf < 4; ++kf) {
                f32x4 pl = pA[kf * 2], ph = pA[kf * 2 + 1];
                f32x4 wl = wvb4[kf * 2], wh = wvb4[kf * 2 + 1];
                float h0 = fmaxf(0.f, fmaf(bp, wl[0], pl[0]));
                float h1 = fmaxf(0.f, fmaf(bp, wl[1], pl[1]));
                float h2 = fmaxf(0.f, fmaf(bp, wl[2], pl[2]));
                float h3 = fmaxf(0.f, fmaf(bp, wl[3], pl[3]));
                float h4 = fmaxf(0.f, fmaf(bp, wh[0], ph[0]));
                float h5 = fmaxf(0.f, fmaf(bp, wh[1], ph[1]));
                float h6 = fmaxf(0.f, fmaf(bp, wh[2], ph[2]));
                float h7 = fmaxf(0.f, fmaf(bp, wh[3], ph[3]));
                union { uint4 u; short8v s; } cv;
                cv.u = make_uint4(cvt_pk_bf16(h0, h1), cvt_pk_bf16(h2, h3),
                                  cvt_pk_bf16(h4, h5), cvt_pk_bf16(h6, h7));
                Bf[kf] = cv.s;
            }
            // advance p1 ring
#pragma unroll
            for (int k2i = 0; k2i < 8; ++k2i) pA[k2i] = pB[k2i];
            if (t < 510) {
#pragma unroll
                for (int k2i = 0; k2i < 8; ++k2i)
                    pB[k2i] = __builtin_bit_cast(f32x4,
                        *(const float4*)&p1base[(size_t)(t + 2) * 2048 +
                                                (k2i >> 1) * 32 + (k2i & 1) * 4]);
            }
            // prefetch bp for step t+1 (po(t+1)=poNxt; <=t-1 entries already in LDS)
            float bpN = 0.f;
            if (poNxt >= 0 && poNxt < t) bpN = bhL[cb * 512 + poNxt];

            f32x4 C[8];
#pragma unroll
            for (int m = 0; m < 8; ++m) C[m] = b2C[m];
#pragma unroll
            for (int kf = 0; kf < 4; ++kf)
#pragma unroll
                for (int m = 0; m < 8; ++m)
                    C[m] = __builtin_amdgcn_mfma_f32_16x16x32_bf16(aH[m][kf], Bf[kf], C[m], 0, 0, 0);

            float part = 0.f;
#pragma unroll
            for (int m = 0; m < 8; ++m)
#pragma unroll
                for (int i = 0; i < 4; ++i)
                    part = fmaf(fmaxf(C[m][i], 0.f), w3C[m][i], part);
            part += __shfl_xor(part, 16);
            part += __shfl_xor(part, 32);
            float bta = part + b3v;
            if (qq == 0) bhL[cb * 512 + t] = bta;
            btap = bta;
            bpPre = bpN;
            poCur = poNxt;
            if (t < 510) poNxt = POg[(t + 2) * 16 + cb];
        }
        for (int i = tid * 4; i < 8192; i += 256)
            *(float4*)&beta_out[i] = *(const float4*)&bhL[i];
    }
}

// ============ K2b: dense C fill (zeros + latest-occurrence betas) ============
__global__ __launch_bounds__(256) void k2b_fill(
    const int* __restrict__ c_seq, const float* __restrict__ beta_in,
    float* __restrict__ C_out)
{
    __shared__ int   scs[Sq];
    __shared__ float sbt[Sq];
    const int bid = blockIdx.x, tid = threadIdx.x;
    const int b = bid / 40, rem = bid % 40;
    const int chunk = rem >> 2, q = rem & 3;

    for (int i = tid; i < Sq; i += 256) {
        scs[i] = c_seq[b * Sq + i];
        sbt[i] = beta_in[b * Sq + i];
    }
    __syncthreads();

    const int c0 = chunk * 1024 + tid * 4;
    if (c0 >= NCq) return;

    float cur0 = 0.f, cur1 = 0.f, cur2 = 0.f, cur3 = 0.f;
    const int tlo = q * 128, thi = tlo + 128;
    float* base = C_out + (size_t)b * Sq * NCq + c0;

    for (int t = 0; t < tlo; ++t) {
        int ct = scs[t] - c0; float bv = sbt[t];
        cur0 = (ct == 0) ? bv : cur0;
        cur1 = (ct == 1) ? bv : cur1;
        cur2 = (ct == 2) ? bv : cur2;
        cur3 = (ct == 3) ? bv : cur3;
    }
    for (int t = tlo; t < thi; ++t) {
        int ct = scs[t] - c0; float bv = sbt[t];
        cur0 = (ct == 0) ? bv : cur0;
        cur1 = (ct == 1) ? bv : cur1;
        cur2 = (ct == 2) ? bv : cur2;
        cur3 = (ct == 3) ? bv : cur3;
        *(float4*)(base + (size_t)t * NCq) = make_float4(cur0, cur1, cur2, cur3);
    }
}

// ============ K3: alpha = mlp1(h_seq) ============
__global__ __launch_bounds__(256) void k3_alpha(
    const float* __restrict__ hseq,
    const float* __restrict__ W1, const float* __restrict__ b1,
    const float* __restrict__ W2, const float* __restrict__ b2,
    const float* __restrict__ W3, const float* __restrict__ b3,
    float* __restrict__ alpha_out)
{
    __shared__ float Hs[32 * 128];
    __shared__ float T1[32 * 128];
    __shared__ float red[4][16];
    const int blk = blockIdx.x, tid = threadIdx.x;
    const int row0 = blk * 32;

    for (int e = tid; e < 1024; e += 256) {
        int r = e >> 5, q = e & 31;
        *(float4*)&Hs[r * 128 + 4 * q] =
            *(const float4*)&hseq[(size_t)(row0 + r) * 128 + 4 * q];
    }
    __syncthreads();

    const int j = tid & 127, rh = tid >> 7;
    const float b1j = b1[j], b2j = b2[j], w3j = W3[j];
    float acc[16];
#pragma unroll
    for (int r = 0; r < 16; ++r) acc[r] = b1j;
    for (int k = 0; k < 128; ++k) {
        float w = W1[k * 128 + j];
#pragma unroll
        for (int r = 0; r < 16; ++r)
            acc[r] = fmaf(Hs[(rh * 16 + r) * 128 + k], w, acc[r]);
    }
#pragma unroll
    for (int r = 0; r < 16; ++r) {
        acc[r] = fmaxf(acc[r], 0.f);
        T1[(rh * 16 + r) * 128 + j] = acc[r];
    }
    __syncthreads();
    float acc2[16];
#pragma unroll
    for (int r = 0; r < 16; ++r) acc2[r] = b2j;
    for (int k = 0; k < 128; ++k) {
        float w = W2[k * 128 + j];
#pragma unroll
        for (int r = 0; r < 16; ++r)
            acc2[r] = fmaf(T1[(rh * 16 + r) * 128 + k], w, acc2[r]);
    }
#pragma unroll
    for (int r = 0; r < 16; ++r) {
        float p = fmaxf(acc2[r], 0.f) * w3j;
#pragma unroll
        for (int off = 1; off < 64; off <<= 1) p += __shfl_xor(p, off);
        if ((tid & 63) == 0) red[tid >> 6][r] = p;
    }
    __syncthreads();
    if (tid < 32) {
        int rr = tid & 15, g = tid >> 4;
        alpha_out[row0 + g * 16 + rr] = red[2 * g][rr] + red[2 * g + 1][rr] + b3[0];
    }
}

extern "C" void kernel_launch(void* const* d_in, const int* in_sizes, int n_in,
                              void* d_out, int out_size, void* d_ws, size_t ws_size,
                              hipStream_t stream) {
    const int*   c_seq = (const int*)d_in[0];
    const int*   d_seq = (const int*)d_in[1];
    const float* r_seq = (const float*)d_in[2];
    const float* D1_w  = (const float*)d_in[3];
    const float* D2_w  = (const float*)d_in[4];
    const float* v_r   = (const float*)d_in[5];
    const float* v_b   = (const float*)d_in[6];
    const float* W_ih  = (const float*)d_in[7];
    const float* W_hh  = (const float*)d_in[8];
    const float* b_ih  = (const float*)d_in[9];
    const float* b_hh  = (const float*)d_in[10];
    const float* m1W1  = (const float*)d_in[11];
    const float* m1b1  = (const float*)d_in[12];
    const float* m1W2  = (const float*)d_in[13];
    const float* m1b2  = (const float*)d_in[14];
    const float* m1W3  = (const float*)d_in[15];
    const float* m1b3  = (const float*)d_in[16];
    const float* m2W1  = (const float*)d_in[17];
    const float* m2b1  = (const float*)d_in[18];
    const float* m2W2  = (const float*)d_in[19];
    const float* m2b2  = (const float*)d_in[20];
    const float* m2W3  = (const float*)d_in[21];
    const float* m2b3  = (const float*)d_in[22];

    float* out   = (float*)d_out;
    float* alpha = out;                 // [16*512]
    float* beta  = out + 8192;          // [16*512]
    float* gamma = out + 16384;         // [16*512]
    float* hseq  = out + 24576;         // [16*512*128]
    float* Cseq  = out + 1073152;       // [16*512*10000]
    float* ws    = (float*)d_ws;

    hipLaunchKernelGGL(k0_prep, dim3(161), dim3(256), 0, stream,
                       c_seq, d_seq, D1_w, W_ih, v_r, v_b, m2W1, ws, gamma);
    hipLaunchKernelGGL(k1_gemm, dim3(1024), dim3(256), 0, stream,
                       d_seq, D2_w, m2W1, b_ih, b_hh, r_seq, m2b1, ws);
    hipLaunchKernelGGL(k2_scan, dim3(5), dim3(512), 0, stream,
                       W_hh, b_hh, m2W2, m2b2, m2W3, m2b3, ws, hseq, beta);
    hipLaunchKernelGGL(k2b_fill, dim3(640), dim3(256), 0, stream,
                       c_seq, beta, Cseq);
    hipLaunchKernelGGL(k3_alpha, dim3(256), dim3(256), 0, stream,
                       hseq, m1W1, m1b1, m1W2, m1b2, m1W3, m1b3, alpha);
}

// Round 12
// 734.375 us; speedup vs baseline: 1.7116x; 1.7116x over previous
//
#include <hip/hip_runtime.h>

#define Bq   16
#define Sq   512
#define Vq   128
#define NCq  10000

typedef __attribute__((ext_vector_type(8))) short short8v;
typedef __attribute__((ext_vector_type(4))) float f32x4;

// ---- workspace layout (float offsets) ----
#define OFF_XPF    0u          // [4 bg][512 t][96 r4][4 b][4 e] f32 (biases + r*wvr folded)
#define OFF_P1F    3145728u    // [512 t][16 b][128 j] f32 (b1 + r*wvr1 folded)
#define OFF_WTIH   4194304u    // [128 k][384 g] W_ih[:, :V]^T
#define OFF_WVRIH  4243456u    // [384]
#define OFF_WVR1   4243840u    // [128]
#define OFF_WVB    4243968u    // [128]
#define OFF_W2T    4244096u    // [128 j][128 k]  W2 transposed
#define OFF_LIST   4260480u    // int2 [16][512]  (t, po) links, ascending t
#define OFF_CNT    4276864u    // int [16]

#define PLN 136
#define PLSZ (16*PLN+8)

__device__ __forceinline__ unsigned cvt_pk_bf16(float a, float b) {
    unsigned r;
    asm("v_cvt_pk_bf16_f32 %0, %1, %2" : "=v"(r) : "v"(a), "v"(b));
    return r;
}
__device__ __forceinline__ void barrier_lgkm() {
    asm volatile("s_waitcnt lgkmcnt(0)" ::: "memory");
    __builtin_amdgcn_sched_barrier(0);
    __builtin_amdgcn_s_barrier();
    __builtin_amdgcn_sched_barrier(0);
}
__device__ __forceinline__ void wait_vm4() {
    asm volatile("s_waitcnt vmcnt(4)" ::: "memory");
    __builtin_amdgcn_sched_barrier(0);
}
__device__ __forceinline__ void gload_lds16(const void* g, void* l) {
    __builtin_amdgcn_global_load_lds(
        (const __attribute__((address_space(1))) unsigned int*)g,
        (__attribute__((address_space(3))) unsigned int*)l, 16, 0, 0);
}

// ============ K0: transposes, small vectors, link lists, gamma ============
__global__ __launch_bounds__(256) void k0_prep(
    const int* __restrict__ c_seq, const int* __restrict__ d_seq,
    const float* __restrict__ D1_w,
    const float* __restrict__ W_ih,
    const float* __restrict__ v_r, const float* __restrict__ v_beta,
    const float* __restrict__ m2W1, const float* __restrict__ m2W2,
    float* __restrict__ ws, float* __restrict__ gamma_out)
{
    const int blk = blockIdx.x, tid = threadIdx.x;

    if (blk < 128) {
        float* WTIH = ws + OFF_WTIH;
        int base = blk * 384;
        for (int i = tid; i < 384; i += 256) {
            int e = base + i;
            int k = e / 384, g = e % 384;
            WTIH[e] = W_ih[g * 256 + k];
        }
    } else if (blk == 128) {
        float* WVRIH = ws + OFF_WVRIH;
        float* WVR1  = ws + OFF_WVR1;
        float* WVB   = ws + OFF_WVB;
        for (int g = tid; g < 384; g += 256) {
            float a = 0.f;
            for (int k = 0; k < 128; ++k) a = fmaf(v_r[k], W_ih[g * 256 + 128 + k], a);
            WVRIH[g] = a;
        }
        if (tid < 128) {
            float a = 0.f, b = 0.f;
            for (int k = 0; k < 128; ++k) {
                a = fmaf(v_r[k],    m2W1[(256 + k) * 128 + tid], a);
                b = fmaf(v_beta[k], m2W1[k * 128 + tid],         b);
            }
            WVR1[tid] = a; WVB[tid] = b;
        }
    } else if (blk < 145) {
        const int b = blk - 129;
        __shared__ int cs[Sq];
        __shared__ int po[Sq];
        for (int i = tid; i < Sq; i += 256) cs[i] = c_seq[b * Sq + i];
        __syncthreads();
        for (int t = tid; t < Sq; t += 256) {
            int c = cs[t];
            int p = -1;
            for (int u = t - 1; u >= 0; --u) if (cs[u] == c) { p = u; break; }
            po[t] = p;
        }
        __syncthreads();
        if (tid == 0) {
            int2* L = (int2*)(ws + OFF_LIST) + b * 512;
            int n = 0;
            for (int t = 0; t < Sq; ++t)
                if (po[t] >= 0) { L[n] = make_int2(t, po[t]); ++n; }
            ((int*)(ws + OFF_CNT))[b] = n;
        }
    } else if (blk < 161) {
        const int b = blk - 145;
        for (int s = tid; s < Sq; s += 256)
            gamma_out[b * Sq + s] = D1_w[d_seq[b * Sq + s]];
    } else {
        // W2T[j][k] = m2W2[k*128 + j]
        float* W2T = ws + OFF_W2T;
        for (int i = tid; i < 16384; i += 256) {
            int j = i >> 7, k = i & 127;
            W2T[i] = m2W2[k * 128 + j];
        }
    }
}

// ============ K1: batched GEMM -> XPF (f32) | P1F (f32), biases folded ============
__global__ __launch_bounds__(256) void k1_gemm(
    const int* __restrict__ d_seq, const float* __restrict__ D2_w,
    const float* __restrict__ m2W1,
    const float* __restrict__ b_ih, const float* __restrict__ b_hh,
    const float* __restrict__ r_seq, const float* __restrict__ m2b1,
    float* __restrict__ ws)
{
    __shared__ float As[64 * 128];
    __shared__ float Bs[128 * 64];
    const int blk = blockIdx.x, tid = threadIdx.x;
    const int nc = blk & 7;
    const int m0 = (blk >> 3) * 64;
    const float* WTIH = ws + OFF_WTIH;

    const float4* D2v = (const float4*)D2_w;
    for (int e = tid; e < 2048; e += 256) {
        int r = e >> 5, q = e & 31;
        int d = d_seq[m0 + r];
        *(float4*)&As[r * 128 + 4 * q] = D2v[d * 32 + q];
    }
    for (int e = tid; e < 2048; e += 256) {
        int k = e >> 4, q = e & 15;
        float4 v;
        if (nc < 6) v = *(const float4*)&WTIH[k * 384 + nc * 64 + 4 * q];
        else        v = *(const float4*)&m2W1[(128 + k) * 128 + (nc - 6) * 64 + 4 * q];
        *(float4*)&Bs[k * 64 + 4 * q] = v;
    }
    __syncthreads();

    const int tx = tid & 15, ty = tid >> 4;
    const int c0 = 4 * tx, r0 = 4 * ty;
    float acc[4][4];
#pragma unroll
    for (int i = 0; i < 4; ++i)
#pragma unroll
        for (int j = 0; j < 4; ++j) acc[i][j] = 0.f;

    for (int k = 0; k < 128; ++k) {
        float4 bv = *(const float4*)&Bs[k * 64 + c0];
#pragma unroll
        for (int i = 0; i < 4; ++i) {
            float a = As[(r0 + i) * 128 + k];
            acc[i][0] = fmaf(a, bv.x, acc[i][0]);
            acc[i][1] = fmaf(a, bv.y, acc[i][1]);
            acc[i][2] = fmaf(a, bv.z, acc[i][2]);
            acc[i][3] = fmaf(a, bv.w, acc[i][3]);
        }
    }

    float rsv[4];
#pragma unroll
    for (int i = 0; i < 4; ++i) rsv[i] = r_seq[m0 + r0 + i];

    if (nc < 6) {
        const int grow0 = nc * 64 + c0;
        float4 bi  = *(const float4*)&b_ih[grow0];
        float4 wv4 = *(const float4*)&(ws + OFF_WVRIH)[grow0];
        float4 bh4 = make_float4(0.f, 0.f, 0.f, 0.f);
        if (nc < 4) bh4 = *(const float4*)&b_hh[grow0];   // r,z gates get b_hh folded
        float* XPF = ws + OFF_XPF;
        const int r4 = grow0 >> 2;
#pragma unroll
        for (int i = 0; i < 4; ++i) {
            int row = m0 + r0 + i;
            int t = row & 511, bb = row >> 9;
            float4 v;
            v.x = acc[i][0] + bi.x + bh4.x + rsv[i] * wv4.x;
            v.y = acc[i][1] + bi.y + bh4.y + rsv[i] * wv4.y;
            v.z = acc[i][2] + bi.z + bh4.z + rsv[i] * wv4.z;
            v.w = acc[i][3] + bi.w + bh4.w + rsv[i] * wv4.w;
            *(float4*)&XPF[((size_t)((bb >> 2) * 512 + t)) * 1536 + r4 * 16 + (bb & 3) * 4] = v;
        }
    } else {
        const int j0 = (nc - 6) * 64 + c0;
        float4 b1v = *(const float4*)&m2b1[j0];
        float4 wr1 = *(const float4*)&(ws + OFF_WVR1)[j0];
        float* P1F = ws + OFF_P1F;
#pragma unroll
        for (int i = 0; i < 4; ++i) {
            int row = m0 + r0 + i;
            int t = row & 511, bb = row >> 9;
            float4 v;
            v.x = acc[i][0] + b1v.x + rsv[i] * wr1.x;
            v.y = acc[i][1] + b1v.y + rsv[i] * wr1.y;
            v.z = acc[i][2] + b1v.z + rsv[i] * wr1.z;
            v.w = acc[i][3] + b1v.w + rsv[i] * wr1.w;
            *(float4*)&P1F[((size_t)(t * 16 + bb)) * 128 + j0] = v;
        }
    }
}

// ============ K2: blk 0..3 GRU (unchanged from R10). blk 4..259: dense beta_nz ============
__global__ __launch_bounds__(512, 1) void k2_scan(
    const float* __restrict__ W_hh, const float* __restrict__ b_hh,
    const float* __restrict__ m2b2, const float* __restrict__ m2W3,
    const float* __restrict__ m2b3,
    float* __restrict__ ws,
    float* __restrict__ hseq_out, float* __restrict__ beta_out)
{
    __shared__ __align__(16) unsigned char smem[41504];
    const int tid = threadIdx.x;
    const int l = tid & 63, wv = tid >> 6;
    const int qq = l >> 4, cb = l & 15;
    const int bgid = blockIdx.x;

    if (bgid < 4) {
        // ---------------- GRU, batches 4*bgid .. 4*bgid+3 (R10-identical) ----------------
        unsigned short* hP  = (unsigned short*)smem;                // [2][PLSZ]
        unsigned char*  xsl = smem + 8736;                          // 4 slots x 8192 B
        const float* XPF = ws + OFF_XPF;

        short8v aH0[4], aH1[4], aH2[4];
#pragma unroll
        for (int kf = 0; kf < 4; ++kf) {
            const int kb = kf * 32 + qq * 8;
            const float* w0 = W_hh + (0 * 128 + 16 * wv + cb) * 128 + kb;
            const float* w1 = W_hh + (1 * 128 + 16 * wv + cb) * 128 + kb;
            const float* w2 = W_hh + (2 * 128 + 16 * wv + cb) * 128 + kb;
            short8v h0, h1, h2;
#pragma unroll
            for (int e = 0; e < 8; ++e) {
                unsigned u0 = __builtin_bit_cast(unsigned, w0[e]);
                unsigned u1 = __builtin_bit_cast(unsigned, w1[e]);
                unsigned u2 = __builtin_bit_cast(unsigned, w2[e]);
                h0[e] = (short)((u0 + 0x7fffu + ((u0 >> 16) & 1u)) >> 16);
                h1[e] = (short)((u1 + 0x7fffu + ((u1 >> 16) & 1u)) >> 16);
                h2[e] = (short)((u2 + 0x7fffu + ((u2 >> 16) & 1u)) >> 16);
            }
            aH0[kf] = h0; aH1[kf] = h1; aH2[kf] = h2;
        }
        f32x4 bhn4;
        {
            float4 t4 = *(const float4*)&b_hh[256 + 16 * wv + 4 * qq];
            bhn4[0] = t4.x; bhn4[1] = t4.y; bhn4[2] = t4.z; bhn4[3] = t4.w;
        }

        float* hp = hseq_out + ((size_t)((bgid * 4 + (cb & 3)) * 512)) * 128 + 16 * wv + 4 * qq;
        float hold[4] = {0.f, 0.f, 0.f, 0.f};
        for (int i = tid; i < 2 * PLSZ; i += 512) hP[i] = 0;
#pragma unroll
        for (int s = 0; s < 3; ++s)
            gload_lds16(XPF + ((size_t)(bgid * 512 + s)) * 1536 + tid * 4,
                        xsl + s * 8192 + tid * 16);
        __syncthreads();

        const float NL2E = -1.44269504f, L2E2 = 2.88539008f;
        for (int t = 0; t < 512; ++t) {
            if (t < 509)
                gload_lds16(XPF + ((size_t)(bgid * 512 + t + 3)) * 1536 + tid * 4,
                            xsl + ((t + 3) & 3) * 8192 + tid * 16);

            const float* xc = (const float*)(xsl + (t & 3) * 8192) +
                              (4 * wv + qq) * 16 + (cb & 3) * 4;
            f32x4 px0 = *(const f32x4*)(xc);
            f32x4 px1 = *(const f32x4*)(xc + 512);
            f32x4 px2 = *(const f32x4*)(xc + 1024);

            const unsigned short* HI = hP + (t & 1) * PLSZ;
            unsigned short* HIn = hP + ((t + 1) & 1) * PLSZ;

            f32x4 C0a = px0, C1a = px1, C2a = bhn4;
            f32x4 C0b = {0.f,0.f,0.f,0.f}, C1b = {0.f,0.f,0.f,0.f}, C2b = {0.f,0.f,0.f,0.f};
            {
                short8v B0 = *(const short8v*)(HI + cb * PLN + 0 * 32 + qq * 8);
                short8v B1 = *(const short8v*)(HI + cb * PLN + 1 * 32 + qq * 8);
                short8v B2 = *(const short8v*)(HI + cb * PLN + 2 * 32 + qq * 8);
                short8v B3 = *(const short8v*)(HI + cb * PLN + 3 * 32 + qq * 8);
                C0a = __builtin_amdgcn_mfma_f32_16x16x32_bf16(aH0[0], B0, C0a, 0, 0, 0);
                C1a = __builtin_amdgcn_mfma_f32_16x16x32_bf16(aH1[0], B0, C1a, 0, 0, 0);
                C2a = __builtin_amdgcn_mfma_f32_16x16x32_bf16(aH2[0], B0, C2a, 0, 0, 0);
                C0b = __builtin_amdgcn_mfma_f32_16x16x32_bf16(aH0[1], B1, C0b, 0, 0, 0);
                C1b = __builtin_amdgcn_mfma_f32_16x16x32_bf16(aH1[1], B1, C1b, 0, 0, 0);
                C2b = __builtin_amdgcn_mfma_f32_16x16x32_bf16(aH2[1], B1, C2b, 0, 0, 0);
                C0a = __builtin_amdgcn_mfma_f32_16x16x32_bf16(aH0[2], B2, C0a, 0, 0, 0);
                C1a = __builtin_amdgcn_mfma_f32_16x16x32_bf16(aH1[2], B2, C1a, 0, 0, 0);
                C2a = __builtin_amdgcn_mfma_f32_16x16x32_bf16(aH2[2], B2, C2a, 0, 0, 0);
                C0b = __builtin_amdgcn_mfma_f32_16x16x32_bf16(aH0[3], B3, C0b, 0, 0, 0);
                C1b = __builtin_amdgcn_mfma_f32_16x16x32_bf16(aH1[3], B3, C1b, 0, 0, 0);
                C2b = __builtin_amdgcn_mfma_f32_16x16x32_bf16(aH2[3], B3, C2b, 0, 0, 0);
            }
            float hnew[4];
#pragma unroll
            for (int i = 0; i < 4; ++i) {
                float pr = C0a[i] + C0b[i];
                float pz = C1a[i] + C1b[i];
                float hn = C2a[i] + C2b[i];
                float r = __builtin_amdgcn_rcpf(1.f + __builtin_amdgcn_exp2f(pr * NL2E));
                float z = __builtin_amdgcn_rcpf(1.f + __builtin_amdgcn_exp2f(pz * NL2E));
                float npre = fmaf(r, hn, px2[i]);
                float n = fmaf(-2.f, __builtin_amdgcn_rcpf(1.f + __builtin_amdgcn_exp2f(npre * L2E2)), 1.f);
                float hv = fmaf(z, hold[i] - n, n);
                hold[i] = hv;
                hnew[i] = hv;
            }
            if (cb < 4) {
                *(float4*)hp = make_float4(hnew[0], hnew[1], hnew[2], hnew[3]);
                uint2 hw;
                hw.x = cvt_pk_bf16(hnew[0], hnew[1]);
                hw.y = cvt_pk_bf16(hnew[2], hnew[3]);
                *(uint2*)(HIn + cb * PLN + 16 * wv + 4 * qq) = hw;
            }
            hp += 128;
            wait_vm4();
            barrier_lgkm();
        }
    } else {
        // ---------------- dense beta_nz: rows 32*(bgid-4) .. +31 of P1F ----------------
        const int d = bgid - 4;
        float* h1L = (float*)smem;                       // [32][128] = 16 KB
        const float* P1F = ws + OFF_P1F;
        const float* W2T = ws + OFF_W2T;

        const float* src = P1F + (size_t)d * 4096;
        for (int i = tid; i < 1024; i += 512) {
            float4 v = *(const float4*)&src[i * 4];
            v.x = fmaxf(v.x, 0.f); v.y = fmaxf(v.y, 0.f);
            v.z = fmaxf(v.z, 0.f); v.w = fmaxf(v.w, 0.f);
            *(float4*)&h1L[i * 4] = v;
        }
        __syncthreads();

        const int r = tid >> 4, jg = tid & 15;
        float acc[8];
#pragma unroll
        for (int jj = 0; jj < 8; ++jj) acc[jj] = m2b2[jg * 8 + jj];
        for (int k4 = 0; k4 < 32; ++k4) {
            float4 h4 = *(const float4*)&h1L[r * 128 + k4 * 4];
#pragma unroll
            for (int jj = 0; jj < 8; ++jj) {
                float4 w4 = *(const float4*)&W2T[(jg * 8 + jj) * 128 + k4 * 4];
                acc[jj] = fmaf(h4.x, w4.x, acc[jj]);
                acc[jj] = fmaf(h4.y, w4.y, acc[jj]);
                acc[jj] = fmaf(h4.z, w4.z, acc[jj]);
                acc[jj] = fmaf(h4.w, w4.w, acc[jj]);
            }
        }
        float part = 0.f;
#pragma unroll
        for (int jj = 0; jj < 8; ++jj)
            part = fmaf(fmaxf(acc[jj], 0.f), m2W3[jg * 8 + jj], part);
        part += __shfl_xor(part, 1);
        part += __shfl_xor(part, 2);
        part += __shfl_xor(part, 4);
        part += __shfl_xor(part, 8);
        if (jg == 0) {
            int R = d * 32 + r;
            beta_out[(R & 15) * 512 + (R >> 4)] = part + m2b3[0];
        }
    }
}

// ============ K2c: sequential fix-up of rare repeat-links (1 wave per batch) ============
__global__ __launch_bounds__(64, 1) void k2c_fix(
    const float* __restrict__ m2b2, const float* __restrict__ m2W3,
    const float* __restrict__ m2b3,
    float* __restrict__ ws, float* __restrict__ beta_out)
{
    __shared__ __align__(16) float W2L[128 * 129];   // +1-pad rows: 2-way banks (free)
    __shared__ float betaF[512];
    __shared__ __align__(16) float h1L[128];
    const int b = blockIdx.x, l = threadIdx.x;
    const float* W2T = ws + OFF_W2T;
    const float* P1F = ws + OFF_P1F;

    for (int i = l; i < 16384; i += 64) {
        int j = i >> 7, k = i & 127;
        W2L[j * 129 + k] = W2T[i];
    }
    for (int i = l; i < 512; i += 64) betaF[i] = beta_out[b * 512 + i];

    const float2 wvb2 = *(const float2*)&(ws + OFF_WVB)[2 * l];
    const float2 b22  = *(const float2*)&m2b2[2 * l];
    const float2 w32  = *(const float2*)&m2W3[2 * l];
    const float b3v = m2b3[0];
    const int n = ((const int*)(ws + OFF_CNT))[b];
    const int2* L = (const int2*)(ws + OFF_LIST) + b * 512;
    barrier_lgkm();

    for (int i = 0; i < n; ++i) {
        int2 tp = L[i];
        float bp = betaF[tp.y];
        float2 p1 = *(const float2*)&P1F[((size_t)(tp.x * 16 + b)) * 128 + 2 * l];
        float h0 = fmaxf(0.f, fmaf(bp, wvb2.x, p1.x));
        float h1 = fmaxf(0.f, fmaf(bp, wvb2.y, p1.y));
        *(float2*)&h1L[2 * l] = make_float2(h0, h1);
        barrier_lgkm();
        float a0 = b22.x, a1 = b22.y;
        const float* w0 = &W2L[(2 * l) * 129];
        const float* w1 = &W2L[(2 * l + 1) * 129];
        for (int k4 = 0; k4 < 32; ++k4) {
            float4 h4 = *(const float4*)&h1L[k4 * 4];
            float4 u0 = *(const float4*)&w0[k4 * 4];
            float4 u1 = *(const float4*)&w1[k4 * 4];
            a0 = fmaf(h4.x, u0.x, a0); a0 = fmaf(h4.y, u0.y, a0);
            a0 = fmaf(h4.z, u0.z, a0); a0 = fmaf(h4.w, u0.w, a0);
            a1 = fmaf(h4.x, u1.x, a1); a1 = fmaf(h4.y, u1.y, a1);
            a1 = fmaf(h4.z, u1.z, a1); a1 = fmaf(h4.w, u1.w, a1);
        }
        float part = fmaf(fmaxf(a0, 0.f), w32.x, fmaxf(a1, 0.f) * w32.y);
#pragma unroll
        for (int off = 1; off < 64; off <<= 1) part += __shfl_xor(part, off);
        float bta = part + b3v;
        if (l == 0) {
            betaF[tp.x] = bta;
            beta_out[b * 512 + tp.x] = bta;
        }
        barrier_lgkm();
    }
}

// ============ K2b: dense C fill (zeros + latest-occurrence betas) ============
__global__ __launch_bounds__(256) void k2b_fill(
    const int* __restrict__ c_seq, const float* __restrict__ beta_in,
    float* __restrict__ C_out)
{
    __shared__ int   scs[Sq];
    __shared__ float sbt[Sq];
    const int bid = blockIdx.x, tid = threadIdx.x;
    const int b = bid / 40, rem = bid % 40;
    const int chunk = rem >> 2, q = rem & 3;

    for (int i = tid; i < Sq; i += 256) {
        scs[i] = c_seq[b * Sq + i];
        sbt[i] = beta_in[b * Sq + i];
    }
    __syncthreads();

    const int c0 = chunk * 1024 + tid * 4;
    if (c0 >= NCq) return;

    float cur0 = 0.f, cur1 = 0.f, cur2 = 0.f, cur3 = 0.f;
    const int tlo = q * 128, thi = tlo + 128;
    float* base = C_out + (size_t)b * Sq * NCq + c0;

    for (int t = 0; t < tlo; ++t) {
        int ct = scs[t] - c0; float bv = sbt[t];
        cur0 = (ct == 0) ? bv : cur0;
        cur1 = (ct == 1) ? bv : cur1;
        cur2 = (ct == 2) ? bv : cur2;
        cur3 = (ct == 3) ? bv : cur3;
    }
    for (int t = tlo; t < thi; ++t) {
        int ct = scs[t] - c0; float bv = sbt[t];
        cur0 = (ct == 0) ? bv : cur0;
        cur1 = (ct == 1) ? bv : cur1;
        cur2 = (ct == 2) ? bv : cur2;
        cur3 = (ct == 3) ? bv : cur3;
        *(float4*)(base + (size_t)t * NCq) = make_float4(cur0, cur1, cur2, cur3);
    }
}

// ============ K3: alpha = mlp1(h_seq) ============
__global__ __launch_bounds__(256) void k3_alpha(
    const float* __restrict__ hseq,
    const float* __restrict__ W1, const float* __restrict__ b1,
    const float* __restrict__ W2, const float* __restrict__ b2,
    const float* __restrict__ W3, const float* __restrict__ b3,
    float* __restrict__ alpha_out)
{
    __shared__ float Hs[32 * 128];
    __shared__ float T1[32 * 128];
    __shared__ float red[4][16];
    const int blk = blockIdx.x, tid = threadIdx.x;
    const int row0 = blk * 32;

    for (int e = tid; e < 1024; e += 256) {
        int r = e >> 5, q = e & 31;
        *(float4*)&Hs[r * 128 + 4 * q] =
            *(const float4*)&hseq[(size_t)(row0 + r) * 128 + 4 * q];
    }
    __syncthreads();

    const int j = tid & 127, rh = tid >> 7;
    const float b1j = b1[j], b2j = b2[j], w3j = W3[j];
    float acc[16];
#pragma unroll
    for (int r = 0; r < 16; ++r) acc[r] = b1j;
    for (int k = 0; k < 128; ++k) {
        float w = W1[k * 128 + j];
#pragma unroll
        for (int r = 0; r < 16; ++r)
            acc[r] = fmaf(Hs[(rh * 16 + r) * 128 + k], w, acc[r]);
    }
#pragma unroll
    for (int r = 0; r < 16; ++r) {
        acc[r] = fmaxf(acc[r], 0.f);
        T1[(rh * 16 + r) * 128 + j] = acc[r];
    }
    __syncthreads();
    float acc2[16];
#pragma unroll
    for (int r = 0; r < 16; ++r) acc2[r] = b2j;
    for (int k = 0; k < 128; ++k) {
        float w = W2[k * 128 + j];
#pragma unroll
        for (int r = 0; r < 16; ++r)
            acc2[r] = fmaf(T1[(rh * 16 + r) * 128 + k], w, acc2[r]);
    }
#pragma unroll
    for (int r = 0; r < 16; ++r) {
        float p = fmaxf(acc2[r], 0.f) * w3j;
#pragma unroll
        for (int off = 1; off < 64; off <<= 1) p += __shfl_xor(p, off);
        if ((tid & 63) == 0) red[tid >> 6][r] = p;
    }
    __syncthreads();
    if (tid < 32) {
        int rr = tid & 15, g = tid >> 4;
        alpha_out[row0 + g * 16 + rr] = red[2 * g][rr] + red[2 * g + 1][rr] + b3[0];
    }
}

extern "C" void kernel_launch(void* const* d_in, const int* in_sizes, int n_in,
                              void* d_out, int out_size, void* d_ws, size_t ws_size,
                              hipStream_t stream) {
    const int*   c_seq = (const int*)d_in[0];
    const int*   d_seq = (const int*)d_in[1];
    const float* r_seq = (const float*)d_in[2];
    const float* D1_w  = (const float*)d_in[3];
    const float* D2_w  = (const float*)d_in[4];
    const float* v_r   = (const float*)d_in[5];
    const float* v_b   = (const float*)d_in[6];
    const float* W_ih  = (const float*)d_in[7];
    const float* W_hh  = (const float*)d_in[8];
    const float* b_ih  = (const float*)d_in[9];
    const float* b_hh  = (const float*)d_in[10];
    const float* m1W1  = (const float*)d_in[11];
    const float* m1b1  = (const float*)d_in[12];
    const float* m1W2  = (const float*)d_in[13];
    const float* m1b2  = (const float*)d_in[14];
    const float* m1W3  = (const float*)d_in[15];
    const float* m1b3  = (const float*)d_in[16];
    const float* m2W1  = (const float*)d_in[17];
    const float* m2b1  = (const float*)d_in[18];
    const float* m2W2  = (const float*)d_in[19];
    const float* m2b2  = (const float*)d_in[20];
    const float* m2W3  = (const float*)d_in[21];
    const float* m2b3  = (const float*)d_in[22];

    float* out   = (float*)d_out;
    float* alpha = out;                 // [16*512]
    float* beta  = out + 8192;          // [16*512]
    float* gamma = out + 16384;         // [16*512]
    float* hseq  = out + 24576;         // [16*512*128]
    float* Cseq  = out + 1073152;       // [16*512*10000]
    float* ws    = (float*)d_ws;

    hipLaunchKernelGGL(k0_prep, dim3(162), dim3(256), 0, stream,
                       c_seq, d_seq, D1_w, W_ih, v_r, v_b, m2W1, m2W2, ws, gamma);
    hipLaunchKernelGGL(k1_gemm, dim3(1024), dim3(256), 0, stream,
                       d_seq, D2_w, m2W1, b_ih, b_hh, r_seq, m2b1, ws);
    hipLaunchKernelGGL(k2_scan, dim3(260), dim3(512), 0, stream,
                       W_hh, b_hh, m2b2, m2W3, m2b3, ws, hseq, beta);
    hipLaunchKernelGGL(k2c_fix, dim3(16), dim3(64), 0, stream,
                       m2b2, m2W3, m2b3, ws, beta);
    hipLaunchKernelGGL(k2b_fill, dim3(640), dim3(256), 0, stream,
                       c_seq, beta, Cseq);
    hipLaunchKernelGGL(k3_alpha, dim3(256), dim3(256), 0, stream,
                       hseq, m1W1, m1b1, m1W2, m1b2, m1W3, m1b3, alpha);
}

// Round 13
// 668.796 us; speedup vs baseline: 1.8794x; 1.0981x over previous
//
#include <hip/hip_runtime.h>

#define Bq   16
#define Sq   512
#define Vq   128
#define NCq  10000

typedef __attribute__((ext_vector_type(8))) short short8v;
typedef __attribute__((ext_vector_type(4))) float f32x4;

// ---- workspace layout (float offsets) ----
#define OFF_XPF    0u          // [4 bg][512 t][96 r4][4 b][4 e] f32 (biases + r*wvr folded)
#define OFF_P1F    3145728u    // [512 t][16 b][128 j] f32 (b1 + r*wvr1 folded)
#define OFF_WTIH   4194304u    // [128 k][384 g] W_ih[:, :V]^T
#define OFF_WVRIH  4243456u    // [384]
#define OFF_WVR1   4243840u    // [128]
#define OFF_WVB    4243968u    // [128]
#define OFF_W2T    4244096u    // [128 j][128 k]  W2 transposed
#define OFF_LIST   4260480u    // int2 [16][512]  (t, po) links, ascending t
#define OFF_CNT    4276864u    // int [16]

#define PLN 136
#define PLSZ (16*PLN+8)

__device__ __forceinline__ unsigned cvt_pk_bf16(float a, float b) {
    unsigned r;
    asm("v_cvt_pk_bf16_f32 %0, %1, %2" : "=v"(r) : "v"(a), "v"(b));
    return r;
}
__device__ __forceinline__ void barrier_lgkm() {
    asm volatile("s_waitcnt lgkmcnt(0)" ::: "memory");
    __builtin_amdgcn_sched_barrier(0);
    __builtin_amdgcn_s_barrier();
    __builtin_amdgcn_sched_barrier(0);
}
__device__ __forceinline__ void wait_vm4() {
    asm volatile("s_waitcnt vmcnt(4)" ::: "memory");
    __builtin_amdgcn_sched_barrier(0);
}
__device__ __forceinline__ void gload_lds16(const void* g, void* l) {
    __builtin_amdgcn_global_load_lds(
        (const __attribute__((address_space(1))) unsigned int*)g,
        (__attribute__((address_space(3))) unsigned int*)l, 16, 0, 0);
}

// ============ K0: transposes, small vectors, link lists, gamma ============
__global__ __launch_bounds__(256) void k0_prep(
    const int* __restrict__ c_seq, const int* __restrict__ d_seq,
    const float* __restrict__ D1_w,
    const float* __restrict__ W_ih,
    const float* __restrict__ v_r, const float* __restrict__ v_beta,
    const float* __restrict__ m2W1, const float* __restrict__ m2W2,
    float* __restrict__ ws, float* __restrict__ gamma_out)
{
    const int blk = blockIdx.x, tid = threadIdx.x;

    if (blk < 128) {
        float* WTIH = ws + OFF_WTIH;
        int base = blk * 384;
        for (int i = tid; i < 384; i += 256) {
            int e = base + i;
            int k = e / 384, g = e % 384;
            WTIH[e] = W_ih[g * 256 + k];
        }
    } else if (blk == 128) {
        float* WVRIH = ws + OFF_WVRIH;
        float* WVR1  = ws + OFF_WVR1;
        float* WVB   = ws + OFF_WVB;
        for (int g = tid; g < 384; g += 256) {
            float a = 0.f;
            for (int k = 0; k < 128; ++k) a = fmaf(v_r[k], W_ih[g * 256 + 128 + k], a);
            WVRIH[g] = a;
        }
        if (tid < 128) {
            float a = 0.f, b = 0.f;
            for (int k = 0; k < 128; ++k) {
                a = fmaf(v_r[k],    m2W1[(256 + k) * 128 + tid], a);
                b = fmaf(v_beta[k], m2W1[k * 128 + tid],         b);
            }
            WVR1[tid] = a; WVB[tid] = b;
        }
    } else if (blk < 145) {
        const int b = blk - 129;
        __shared__ int cs[Sq];
        __shared__ int po[Sq];
        for (int i = tid; i < Sq; i += 256) cs[i] = c_seq[b * Sq + i];
        __syncthreads();
        for (int t = tid; t < Sq; t += 256) {
            int c = cs[t];
            int p = -1;
            for (int u = t - 1; u >= 0; --u) if (cs[u] == c) { p = u; break; }
            po[t] = p;
        }
        __syncthreads();
        if (tid == 0) {
            int2* L = (int2*)(ws + OFF_LIST) + b * 512;
            int n = 0;
            for (int t = 0; t < Sq; ++t)
                if (po[t] >= 0) { L[n] = make_int2(t, po[t]); ++n; }
            ((int*)(ws + OFF_CNT))[b] = n;
        }
    } else if (blk < 161) {
        const int b = blk - 145;
        for (int s = tid; s < Sq; s += 256)
            gamma_out[b * Sq + s] = D1_w[d_seq[b * Sq + s]];
    } else {
        // W2T[j][k] = m2W2[k*128 + j]
        float* W2T = ws + OFF_W2T;
        for (int i = tid; i < 16384; i += 256) {
            int j = i >> 7, k = i & 127;
            W2T[i] = m2W2[k * 128 + j];
        }
    }
}

// ============ K1: batched GEMM -> XPF (f32) | P1F (f32), biases folded ============
__global__ __launch_bounds__(256) void k1_gemm(
    const int* __restrict__ d_seq, const float* __restrict__ D2_w,
    const float* __restrict__ m2W1,
    const float* __restrict__ b_ih, const float* __restrict__ b_hh,
    const float* __restrict__ r_seq, const float* __restrict__ m2b1,
    float* __restrict__ ws)
{
    __shared__ float As[64 * 128];
    __shared__ float Bs[128 * 64];
    const int blk = blockIdx.x, tid = threadIdx.x;
    const int nc = blk & 7;
    const int m0 = (blk >> 3) * 64;
    const float* WTIH = ws + OFF_WTIH;

    const float4* D2v = (const float4*)D2_w;
    for (int e = tid; e < 2048; e += 256) {
        int r = e >> 5, q = e & 31;
        int d = d_seq[m0 + r];
        *(float4*)&As[r * 128 + 4 * q] = D2v[d * 32 + q];
    }
    for (int e = tid; e < 2048; e += 256) {
        int k = e >> 4, q = e & 15;
        float4 v;
        if (nc < 6) v = *(const float4*)&WTIH[k * 384 + nc * 64 + 4 * q];
        else        v = *(const float4*)&m2W1[(128 + k) * 128 + (nc - 6) * 64 + 4 * q];
        *(float4*)&Bs[k * 64 + 4 * q] = v;
    }
    __syncthreads();

    const int tx = tid & 15, ty = tid >> 4;
    const int c0 = 4 * tx, r0 = 4 * ty;
    float acc[4][4];
#pragma unroll
    for (int i = 0; i < 4; ++i)
#pragma unroll
        for (int j = 0; j < 4; ++j) acc[i][j] = 0.f;

    for (int k = 0; k < 128; ++k) {
        float4 bv = *(const float4*)&Bs[k * 64 + c0];
#pragma unroll
        for (int i = 0; i < 4; ++i) {
            float a = As[(r0 + i) * 128 + k];
            acc[i][0] = fmaf(a, bv.x, acc[i][0]);
            acc[i][1] = fmaf(a, bv.y, acc[i][1]);
            acc[i][2] = fmaf(a, bv.z, acc[i][2]);
            acc[i][3] = fmaf(a, bv.w, acc[i][3]);
        }
    }

    float rsv[4];
#pragma unroll
    for (int i = 0; i < 4; ++i) rsv[i] = r_seq[m0 + r0 + i];

    if (nc < 6) {
        const int grow0 = nc * 64 + c0;
        float4 bi  = *(const float4*)&b_ih[grow0];
        float4 wv4 = *(const float4*)&(ws + OFF_WVRIH)[grow0];
        float4 bh4 = make_float4(0.f, 0.f, 0.f, 0.f);
        if (nc < 4) bh4 = *(const float4*)&b_hh[grow0];   // r,z gates get b_hh folded
        float* XPF = ws + OFF_XPF;
        const int r4 = grow0 >> 2;
#pragma unroll
        for (int i = 0; i < 4; ++i) {
            int row = m0 + r0 + i;
            int t = row & 511, bb = row >> 9;
            float4 v;
            v.x = acc[i][0] + bi.x + bh4.x + rsv[i] * wv4.x;
            v.y = acc[i][1] + bi.y + bh4.y + rsv[i] * wv4.y;
            v.z = acc[i][2] + bi.z + bh4.z + rsv[i] * wv4.z;
            v.w = acc[i][3] + bi.w + bh4.w + rsv[i] * wv4.w;
            *(float4*)&XPF[((size_t)((bb >> 2) * 512 + t)) * 1536 + r4 * 16 + (bb & 3) * 4] = v;
        }
    } else {
        const int j0 = (nc - 6) * 64 + c0;
        float4 b1v = *(const float4*)&m2b1[j0];
        float4 wr1 = *(const float4*)&(ws + OFF_WVR1)[j0];
        float* P1F = ws + OFF_P1F;
#pragma unroll
        for (int i = 0; i < 4; ++i) {
            int row = m0 + r0 + i;
            int t = row & 511, bb = row >> 9;
            float4 v;
            v.x = acc[i][0] + b1v.x + rsv[i] * wr1.x;
            v.y = acc[i][1] + b1v.y + rsv[i] * wr1.y;
            v.z = acc[i][2] + b1v.z + rsv[i] * wr1.z;
            v.w = acc[i][3] + b1v.w + rsv[i] * wr1.w;
            *(float4*)&P1F[((size_t)(t * 16 + bb)) * 128 + j0] = v;
        }
    }
}

// ============ K2: blk 0..3 GRU (hseq LDS-staged, 8-slot ring). blk 4..259: dense beta_nz ============
__global__ __launch_bounds__(512, 1) void k2_scan(
    const float* __restrict__ W_hh, const float* __restrict__ b_hh,
    const float* __restrict__ m2b2, const float* __restrict__ m2W3,
    const float* __restrict__ m2b3,
    float* __restrict__ ws,
    float* __restrict__ hseq_out, float* __restrict__ beta_out)
{
    __shared__ __align__(16) unsigned char smem[107040];
    const int tid = threadIdx.x;
    const int l = tid & 63, wv = tid >> 6;
    const int qq = l >> 4, cb = l & 15;
    const int bgid = blockIdx.x;

    if (bgid < 4) {
        // ---------------- GRU, batches 4*bgid .. 4*bgid+3 ----------------
        unsigned short* hP  = (unsigned short*)smem;                // [2][PLSZ] 8736 B
        unsigned char*  xsl = smem + 8736;                          // 8 slots x 8192 B
        float* hstage = (float*)(smem + 8736 + 65536);              // 2 x 4096 f32
        const float* XPF = ws + OFF_XPF;

        short8v aH0[4], aH1[4], aH2[4];
#pragma unroll
        for (int kf = 0; kf < 4; ++kf) {
            const int kb = kf * 32 + qq * 8;
            const float* w0 = W_hh + (0 * 128 + 16 * wv + cb) * 128 + kb;
            const float* w1 = W_hh + (1 * 128 + 16 * wv + cb) * 128 + kb;
            const float* w2 = W_hh + (2 * 128 + 16 * wv + cb) * 128 + kb;
            short8v h0, h1, h2;
#pragma unroll
            for (int e = 0; e < 8; ++e) {
                unsigned u0 = __builtin_bit_cast(unsigned, w0[e]);
                unsigned u1 = __builtin_bit_cast(unsigned, w1[e]);
                unsigned u2 = __builtin_bit_cast(unsigned, w2[e]);
                h0[e] = (short)((u0 + 0x7fffu + ((u0 >> 16) & 1u)) >> 16);
                h1[e] = (short)((u1 + 0x7fffu + ((u1 >> 16) & 1u)) >> 16);
                h2[e] = (short)((u2 + 0x7fffu + ((u2 >> 16) & 1u)) >> 16);
            }
            aH0[kf] = h0; aH1[kf] = h1; aH2[kf] = h2;
        }
        f32x4 bhn4;
        {
            float4 t4 = *(const float4*)&b_hh[256 + 16 * wv + 4 * qq];
            bhn4[0] = t4.x; bhn4[1] = t4.y; bhn4[2] = t4.z; bhn4[3] = t4.w;
        }

        float hold[4] = {0.f, 0.f, 0.f, 0.f};
        for (int i = tid; i < 2 * PLSZ; i += 512) hP[i] = 0;
#pragma unroll
        for (int s = 0; s < 5; ++s)
            gload_lds16(XPF + ((size_t)(bgid * 512 + s)) * 1536 + tid * 4,
                        xsl + s * 8192 + tid * 16);
        __syncthreads();   // drains prologue vmcnt + publishes plane zeros

        const float NL2E = -1.44269504f, L2E2 = 2.88539008f;
        for (int t = 0; t < 512; ++t) {
            if (t < 507)
                gload_lds16(XPF + ((size_t)(bgid * 512 + t + 5)) * 1536 + tid * 4,
                            xsl + ((t + 5) & 7) * 8192 + tid * 16);
            // flush previous 8-step hstage buffer (fire-and-forget stores)
            if ((t & 7) == 0 && t > 0) {
                const float* hb = hstage + (((t >> 3) + 1) & 1) * 4096;
#pragma unroll
                for (int r2 = 0; r2 < 2; ++r2) {
                    int e2 = tid * 2 + r2;
                    int ss = e2 >> 7, bq2 = (e2 >> 5) & 3, q = e2 & 31;
                    float4 v = *(const float4*)&hb[(ss * 4 + bq2) * 128 + q * 4];
                    *(float4*)&hseq_out[((size_t)((bgid * 4 + bq2) * 512 + (t - 8 + ss))) * 128 + q * 4] = v;
                }
            }

            const float* xc = (const float*)(xsl + (t & 7) * 8192) +
                              (4 * wv + qq) * 16 + (cb & 3) * 4;
            f32x4 px0 = *(const f32x4*)(xc);
            f32x4 px1 = *(const f32x4*)(xc + 512);
            f32x4 px2 = *(const f32x4*)(xc + 1024);

            const unsigned short* HI = hP + (t & 1) * PLSZ;
            unsigned short* HIn = hP + ((t + 1) & 1) * PLSZ;

            f32x4 C0a = px0, C1a = px1, C2a = bhn4;
            f32x4 C0b = {0.f,0.f,0.f,0.f}, C1b = {0.f,0.f,0.f,0.f}, C2b = {0.f,0.f,0.f,0.f};
            {
                short8v B0 = *(const short8v*)(HI + cb * PLN + 0 * 32 + qq * 8);
                short8v B1 = *(const short8v*)(HI + cb * PLN + 1 * 32 + qq * 8);
                short8v B2 = *(const short8v*)(HI + cb * PLN + 2 * 32 + qq * 8);
                short8v B3 = *(const short8v*)(HI + cb * PLN + 3 * 32 + qq * 8);
                C0a = __builtin_amdgcn_mfma_f32_16x16x32_bf16(aH0[0], B0, C0a, 0, 0, 0);
                C1a = __builtin_amdgcn_mfma_f32_16x16x32_bf16(aH1[0], B0, C1a, 0, 0, 0);
                C2a = __builtin_amdgcn_mfma_f32_16x16x32_bf16(aH2[0], B0, C2a, 0, 0, 0);
                C0b = __builtin_amdgcn_mfma_f32_16x16x32_bf16(aH0[1], B1, C0b, 0, 0, 0);
                C1b = __builtin_amdgcn_mfma_f32_16x16x32_bf16(aH1[1], B1, C1b, 0, 0, 0);
                C2b = __builtin_amdgcn_mfma_f32_16x16x32_bf16(aH2[1], B1, C2b, 0, 0, 0);
                C0a = __builtin_amdgcn_mfma_f32_16x16x32_bf16(aH0[2], B2, C0a, 0, 0, 0);
                C1a = __builtin_amdgcn_mfma_f32_16x16x32_bf16(aH1[2], B2, C1a, 0, 0, 0);
                C2a = __builtin_amdgcn_mfma_f32_16x16x32_bf16(aH2[2], B2, C2a, 0, 0, 0);
                C0b = __builtin_amdgcn_mfma_f32_16x16x32_bf16(aH0[3], B3, C0b, 0, 0, 0);
                C1b = __builtin_amdgcn_mfma_f32_16x16x32_bf16(aH1[3], B3, C1b, 0, 0, 0);
                C2b = __builtin_amdgcn_mfma_f32_16x16x32_bf16(aH2[3], B3, C2b, 0, 0, 0);
            }
            float hnew[4];
#pragma unroll
            for (int i = 0; i < 4; ++i) {
                float pr = C0a[i] + C0b[i];
                float pz = C1a[i] + C1b[i];
                float hn = C2a[i] + C2b[i];
                float r = __builtin_amdgcn_rcpf(1.f + __builtin_amdgcn_exp2f(pr * NL2E));
                float z = __builtin_amdgcn_rcpf(1.f + __builtin_amdgcn_exp2f(pz * NL2E));
                float npre = fmaf(r, hn, px2[i]);
                float n = fmaf(-2.f, __builtin_amdgcn_rcpf(1.f + __builtin_amdgcn_exp2f(npre * L2E2)), 1.f);
                float hv = fmaf(z, hold[i] - n, n);
                hold[i] = hv;
                hnew[i] = hv;
            }
            if (cb < 4) {
                float* hst = hstage + ((t >> 3) & 1) * 4096;
                *(float4*)&hst[((t & 7) * 4 + cb) * 128 + 16 * wv + 4 * qq] =
                    make_float4(hnew[0], hnew[1], hnew[2], hnew[3]);
                uint2 hw;
                hw.x = cvt_pk_bf16(hnew[0], hnew[1]);
                hw.y = cvt_pk_bf16(hnew[2], hnew[3]);
                *(uint2*)(HIn + cb * PLN + 16 * wv + 4 * qq) = hw;
            }
            wait_vm4();
            barrier_lgkm();
        }
        // epilogue: flush steps 504..511 (buffer 1)
#pragma unroll
        for (int r2 = 0; r2 < 2; ++r2) {
            int e2 = tid * 2 + r2;
            int ss = e2 >> 7, bq2 = (e2 >> 5) & 3, q = e2 & 31;
            float4 v = *(const float4*)&hstage[4096 + (ss * 4 + bq2) * 128 + q * 4];
            *(float4*)&hseq_out[((size_t)((bgid * 4 + bq2) * 512 + (504 + ss))) * 128 + q * 4] = v;
        }
    } else {
        // ---------------- dense beta_nz: rows 32*(bgid-4) .. +31 of P1F ----------------
        const int d = bgid - 4;
        float* h1L = (float*)smem;                       // [32][128] = 16 KB
        const float* P1F = ws + OFF_P1F;
        const float* W2T = ws + OFF_W2T;

        const float* src = P1F + (size_t)d * 4096;
        for (int i = tid; i < 1024; i += 512) {
            float4 v = *(const float4*)&src[i * 4];
            v.x = fmaxf(v.x, 0.f); v.y = fmaxf(v.y, 0.f);
            v.z = fmaxf(v.z, 0.f); v.w = fmaxf(v.w, 0.f);
            *(float4*)&h1L[i * 4] = v;
        }
        __syncthreads();

        const int r = tid >> 4, jg = tid & 15;
        float acc[8];
#pragma unroll
        for (int jj = 0; jj < 8; ++jj) acc[jj] = m2b2[jg * 8 + jj];
        for (int k4 = 0; k4 < 32; ++k4) {
            float4 h4 = *(const float4*)&h1L[r * 128 + k4 * 4];
#pragma unroll
            for (int jj = 0; jj < 8; ++jj) {
                float4 w4 = *(const float4*)&W2T[(jg * 8 + jj) * 128 + k4 * 4];
                acc[jj] = fmaf(h4.x, w4.x, acc[jj]);
                acc[jj] = fmaf(h4.y, w4.y, acc[jj]);
                acc[jj] = fmaf(h4.z, w4.z, acc[jj]);
                acc[jj] = fmaf(h4.w, w4.w, acc[jj]);
            }
        }
        float part = 0.f;
#pragma unroll
        for (int jj = 0; jj < 8; ++jj)
            part = fmaf(fmaxf(acc[jj], 0.f), m2W3[jg * 8 + jj], part);
        part += __shfl_xor(part, 1);
        part += __shfl_xor(part, 2);
        part += __shfl_xor(part, 4);
        part += __shfl_xor(part, 8);
        if (jg == 0) {
            int R = d * 32 + r;
            beta_out[(R & 15) * 512 + (R >> 4)] = part + m2b3[0];
        }
    }
}

// ============ K2c: sequential fix-up of rare repeat-links (1 wave per batch) ============
__global__ __launch_bounds__(64, 1) void k2c_fix(
    const float* __restrict__ m2b2, const float* __restrict__ m2W3,
    const float* __restrict__ m2b3,
    float* __restrict__ ws, float* __restrict__ beta_out)
{
    __shared__ __align__(16) float W2L[128 * 129];   // +1-pad rows
    __shared__ float betaF[512];
    __shared__ __align__(16) float h1L[128];
    const int b = blockIdx.x, l = threadIdx.x;
    const float* W2T = ws + OFF_W2T;
    const float* P1F = ws + OFF_P1F;

    for (int i = l; i < 16384; i += 64) {
        int j = i >> 7, k = i & 127;
        W2L[j * 129 + k] = W2T[i];
    }
    for (int i = l; i < 512; i += 64) betaF[i] = beta_out[b * 512 + i];

    const float2 wvb2 = *(const float2*)&(ws + OFF_WVB)[2 * l];
    const float2 b22  = *(const float2*)&m2b2[2 * l];
    const float2 w32  = *(const float2*)&m2W3[2 * l];
    const float b3v = m2b3[0];
    const int n = ((const int*)(ws + OFF_CNT))[b];
    const int2* L = (const int2*)(ws + OFF_LIST) + b * 512;
    barrier_lgkm();

    for (int i = 0; i < n; ++i) {
        int2 tp = L[i];
        float bp = betaF[tp.y];
        float2 p1 = *(const float2*)&P1F[((size_t)(tp.x * 16 + b)) * 128 + 2 * l];
        float h0 = fmaxf(0.f, fmaf(bp, wvb2.x, p1.x));
        float h1 = fmaxf(0.f, fmaf(bp, wvb2.y, p1.y));
        *(float2*)&h1L[2 * l] = make_float2(h0, h1);
        barrier_lgkm();
        float a0 = b22.x, a1 = b22.y;
        const float* w0 = &W2L[(2 * l) * 129];
        const float* w1 = &W2L[(2 * l + 1) * 129];
        for (int k4 = 0; k4 < 32; ++k4) {
            float4 h4 = *(const float4*)&h1L[k4 * 4];
            float4 u0 = *(const float4*)&w0[k4 * 4];
            float4 u1 = *(const float4*)&w1[k4 * 4];
            a0 = fmaf(h4.x, u0.x, a0); a0 = fmaf(h4.y, u0.y, a0);
            a0 = fmaf(h4.z, u0.z, a0); a0 = fmaf(h4.w, u0.w, a0);
            a1 = fmaf(h4.x, u1.x, a1); a1 = fmaf(h4.y, u1.y, a1);
            a1 = fmaf(h4.z, u1.z, a1); a1 = fmaf(h4.w, u1.w, a1);
        }
        float part = fmaf(fmaxf(a0, 0.f), w32.x, fmaxf(a1, 0.f) * w32.y);
#pragma unroll
        for (int off = 1; off < 64; off <<= 1) part += __shfl_xor(part, off);
        float bta = part + b3v;
        if (l == 0) {
            betaF[tp.x] = bta;
            beta_out[b * 512 + tp.x] = bta;
        }
        barrier_lgkm();
    }
}

// ============ K2b: dense C fill (zeros + latest-occurrence betas) ============
__global__ __launch_bounds__(256) void k2b_fill(
    const int* __restrict__ c_seq, const float* __restrict__ beta_in,
    float* __restrict__ C_out)
{
    __shared__ int   scs[Sq];
    __shared__ float sbt[Sq];
    const int bid = blockIdx.x, tid = threadIdx.x;
    const int b = bid / 40, rem = bid % 40;
    const int chunk = rem >> 2, q = rem & 3;

    for (int i = tid; i < Sq; i += 256) {
        scs[i] = c_seq[b * Sq + i];
        sbt[i] = beta_in[b * Sq + i];
    }
    __syncthreads();

    const int c0 = chunk * 1024 + tid * 4;
    if (c0 >= NCq) return;

    float cur0 = 0.f, cur1 = 0.f, cur2 = 0.f, cur3 = 0.f;
    const int tlo = q * 128, thi = tlo + 128;
    float* base = C_out + (size_t)b * Sq * NCq + c0;

    for (int t = 0; t < tlo; ++t) {
        int ct = scs[t] - c0; float bv = sbt[t];
        cur0 = (ct == 0) ? bv : cur0;
        cur1 = (ct == 1) ? bv : cur1;
        cur2 = (ct == 2) ? bv : cur2;
        cur3 = (ct == 3) ? bv : cur3;
    }
    for (int t = tlo; t < thi; ++t) {
        int ct = scs[t] - c0; float bv = sbt[t];
        cur0 = (ct == 0) ? bv : cur0;
        cur1 = (ct == 1) ? bv : cur1;
        cur2 = (ct == 2) ? bv : cur2;
        cur3 = (ct == 3) ? bv : cur3;
        *(float4*)(base + (size_t)t * NCq) = make_float4(cur0, cur1, cur2, cur3);
    }
}

// ============ K3: alpha = mlp1(h_seq) ============
__global__ __launch_bounds__(256) void k3_alpha(
    const float* __restrict__ hseq,
    const float* __restrict__ W1, const float* __restrict__ b1,
    const float* __restrict__ W2, const float* __restrict__ b2,
    const float* __restrict__ W3, const float* __restrict__ b3,
    float* __restrict__ alpha_out)
{
    __shared__ float Hs[32 * 128];
    __shared__ float T1[32 * 128];
    __shared__ float red[4][16];
    const int blk = blockIdx.x, tid = threadIdx.x;
    const int row0 = blk * 32;

    for (int e = tid; e < 1024; e += 256) {
        int r = e >> 5, q = e & 31;
        *(float4*)&Hs[r * 128 + 4 * q] =
            *(const float4*)&hseq[(size_t)(row0 + r) * 128 + 4 * q];
    }
    __syncthreads();

    const int j = tid & 127, rh = tid >> 7;
    const float b1j = b1[j], b2j = b2[j], w3j = W3[j];
    float acc[16];
#pragma unroll
    for (int r = 0; r < 16; ++r) acc[r] = b1j;
    for (int k = 0; k < 128; ++k) {
        float w = W1[k * 128 + j];
#pragma unroll
        for (int r = 0; r < 16; ++r)
            acc[r] = fmaf(Hs[(rh * 16 + r) * 128 + k], w, acc[r]);
    }
#pragma unroll
    for (int r = 0; r < 16; ++r) {
        acc[r] = fmaxf(acc[r], 0.f);
        T1[(rh * 16 + r) * 128 + j] = acc[r];
    }
    __syncthreads();
    float acc2[16];
#pragma unroll
    for (int r = 0; r < 16; ++r) acc2[r] = b2j;
    for (int k = 0; k < 128; ++k) {
        float w = W2[k * 128 + j];
#pragma unroll
        for (int r = 0; r < 16; ++r)
            acc2[r] = fmaf(T1[(rh * 16 + r) * 128 + k], w, acc2[r]);
    }
#pragma unroll
    for (int r = 0; r < 16; ++r) {
        float p = fmaxf(acc2[r], 0.f) * w3j;
#pragma unroll
        for (int off = 1; off < 64; off <<= 1) p += __shfl_xor(p, off);
        if ((tid & 63) == 0) red[tid >> 6][r] = p;
    }
    __syncthreads();
    if (tid < 32) {
        int rr = tid & 15, g = tid >> 4;
        alpha_out[row0 + g * 16 + rr] = red[2 * g][rr] + red[2 * g + 1][rr] + b3[0];
    }
}

extern "C" void kernel_launch(void* const* d_in, const int* in_sizes, int n_in,
                              void* d_out, int out_size, void* d_ws, size_t ws_size,
                              hipStream_t stream) {
    const int*   c_seq = (const int*)d_in[0];
    const int*   d_seq = (const int*)d_in[1];
    const float* r_seq = (const float*)d_in[2];
    const float* D1_w  = (const float*)d_in[3];
    const float* D2_w  = (const float*)d_in[4];
    const float* v_r   = (const float*)d_in[5];
    const float* v_b   = (const float*)d_in[6];
    const float* W_ih  = (const float*)d_in[7];
    const float* W_hh  = (const float*)d_in[8];
    const float* b_ih  = (const float*)d_in[9];
    const float* b_hh  = (const float*)d_in[10];
    const float* m1W1  = (const float*)d_in[11];
    const float* m1b1  = (const float*)d_in[12];
    const float* m1W2  = (const float*)d_in[13];
    const float* m1b2  = (const float*)d_in[14];
    const float* m1W3  = (const float*)d_in[15];
    const float* m1b3  = (const float*)d_in[16];
    const float* m2W1  = (const float*)d_in[17];
    const float* m2b1  = (const float*)d_in[18];
    const float* m2W2  = (const float*)d_in[19];
    const float* m2b2  = (const float*)d_in[20];
    const float* m2W3  = (const float*)d_in[21];
    const float* m2b3  = (const float*)d_in[22];

    float* out   = (float*)d_out;
    float* alpha = out;                 // [16*512]
    float* beta  = out + 8192;          // [16*512]
    float* gamma = out + 16384;         // [16*512]
    float* hseq  = out + 24576;         // [16*512*128]
    float* Cseq  = out + 1073152;       // [16*512*10000]
    float* ws    = (float*)d_ws;

    hipLaunchKernelGGL(k0_prep, dim3(162), dim3(256), 0, stream,
                       c_seq, d_seq, D1_w, W_ih, v_r, v_b, m2W1, m2W2, ws, gamma);
    hipLaunchKernelGGL(k1_gemm, dim3(1024), dim3(256), 0, stream,
                       d_seq, D2_w, m2W1, b_ih, b_hh, r_seq, m2b1, ws);
    hipLaunchKernelGGL(k2_scan, dim3(260), dim3(512), 0, stream,
                       W_hh, b_hh, m2b2, m2W3, m2b3, ws, hseq, beta);
    hipLaunchKernelGGL(k2c_fix, dim3(16), dim3(64), 0, stream,
                       m2b2, m2W3, m2b3, ws, beta);
    hipLaunchKernelGGL(k2b_fill, dim3(640), dim3(256), 0, stream,
                       c_seq, beta, Cseq);
    hipLaunchKernelGGL(k3_alpha, dim3(256), dim3(256), 0, stream,
                       hseq, m1W1, m1b1, m1W2, m1b2, m1W3, m1b3, alpha);
}